// Round 3
// baseline (235.406 us; speedup 1.0000x reference)
//
#include <hip/hip_runtime.h>
#include <hip/hip_bf16.h>

typedef __attribute__((ext_vector_type(8))) short short8;   // 8 bf16 (4 VGPRs) MFMA A/B frag
typedef __attribute__((ext_vector_type(4))) float f32x4;    // MFMA C/D frag

constexpr int B_ROWS   = 524288;
constexpr int ROWTILES = B_ROWS / 64;   // 8192 tiles of 64 rows
constexpr int GRID     = 2048;          // 4 grid-stride iters per block
constexpr float L2E2   = 2.8853900817779268f;  // 2*log2(e)

__device__ __forceinline__ short bf16_rne(float f) {
  union { float f; unsigned u; } v; v.f = f;
  unsigned u = v.u + 0x7FFFu + ((v.u >> 16) & 1u);
  return (short)(u >> 16);
}

__device__ __forceinline__ short8 pack8(f32x4 a, f32x4 b) {
  short8 f;
  f[0] = bf16_rne(a[0]); f[1] = bf16_rne(a[1]);
  f[2] = bf16_rne(a[2]); f[3] = bf16_rne(a[3]);
  f[4] = bf16_rne(b[0]); f[5] = bf16_rne(b[1]);
  f[6] = bf16_rne(b[2]); f[7] = bf16_rne(b[3]);
  return f;
}

// Barrier-free, LDS-free variant.
//   C[n,b] = sum_i W1[n,i]*x[b,i]; out[b,k] = 1 - 1/(exp2(L*S)+1),
//   S = b2 + sum_h w2 - sum_h 2*w2/(exp2(L*c + L*b1)+1)   [folded tanh algebra]
// Wave w owns n in [64w,64w+64) -> classifiers {2w,2w+1}; weights in registers.
// x B-fragments are loaded DIRECTLY from global (lane l reads
// x[row=tile+l&15][k=(l>>4)*8..+7]) — 16B-coalesced; the 4x per-block re-read
// of the same rows is served by L1/L2 (536 MB L2 traffic @34.5 TB/s = 15.5 us,
// under the 21 us HBM floor). No __syncthreads anywhere -> waves slip freely.
__global__ __launch_bounds__(256, 4) void fused_mlp8(
    const float* __restrict__ x, const float* __restrict__ W1,
    const float* __restrict__ b1, const float* __restrict__ W2,
    const float* __restrict__ b2, float* __restrict__ out) {

  const int tid  = threadIdx.x;
  const int wave = tid >> 6;
  const int lane = tid & 63;
  const int m16  = lane & 15;
  const int q    = lane >> 4;

  // ---- W1 A-fragments: lane holds W1[n=(4w+mt)*16+m16][ks*32+q*8 .. +7]
  short8 w1f[4][2];
#pragma unroll
  for (int mt = 0; mt < 4; ++mt) {
    const int n = (wave * 4 + mt) * 16 + m16;
#pragma unroll
    for (int ks = 0; ks < 2; ++ks) {
      const float* p = W1 + n * 64 + ks * 32 + q * 8;
      w1f[mt][ks] = pack8(*(const f32x4*)p, *(const f32x4*)(p + 4));
    }
  }

  // ---- folded per-lane constants for C-layout rows n0 = (4w+mt)*16 + 4q
  f32x4 kb1[4], w2m[4];
  float sw2[2] = {0.f, 0.f};
#pragma unroll
  for (int mt = 0; mt < 4; ++mt) {
    const int n0 = (wave * 4 + mt) * 16 + q * 4;
    const f32x4 b1x = *(const f32x4*)(b1 + n0);
    const f32x4 w2x = *(const f32x4*)(W2 + n0);
#pragma unroll
    for (int r = 0; r < 4; ++r) {
      kb1[mt][r] = L2E2 * b1x[r];
      w2m[mt][r] = -2.0f * w2x[r];
      sw2[mt >> 1] += w2x[r];
    }
  }
  float KSb[2];
#pragma unroll
  for (int j = 0; j < 2; ++j) {
    float s = sw2[j];
    s += __shfl_xor(s, 16);
    s += __shfl_xor(s, 32);
    KSb[j] = L2E2 * (s + b2[wave * 2 + j]);
  }

  for (int it = blockIdx.x; it < ROWTILES; it += GRID) {
    const long base = (long)it * 64;

#pragma unroll
    for (int tt = 0; tt < 4; ++tt) {
      // ---- direct B-fragment load: lane reads row (tt*16+m16), k-halves q*8 / 32+q*8
      const float* rp = x + (base + tt * 16 + m16) * 64 + q * 8;
      const f32x4 a0 = *(const f32x4*)(rp);
      const f32x4 a1 = *(const f32x4*)(rp + 4);
      const f32x4 c0 = *(const f32x4*)(rp + 32);
      const f32x4 c1 = *(const f32x4*)(rp + 36);
      const short8 xf0 = pack8(a0, a1);
      const short8 xf1 = pack8(c0, c1);

      f32x4 acc[4];
#pragma unroll
      for (int mt = 0; mt < 4; ++mt) {
        f32x4 z = { 0.f, 0.f, 0.f, 0.f };
        z = __builtin_amdgcn_mfma_f32_16x16x32_bf16(w1f[mt][0], xf0, z, 0, 0, 0);
        z = __builtin_amdgcn_mfma_f32_16x16x32_bf16(w1f[mt][1], xf1, z, 0, 0, 0);
        acc[mt] = z;
      }

      float o0 = 0.f, o1 = 0.f;
#pragma unroll
      for (int j = 0; j < 2; ++j) {
        float P = 0.f;
#pragma unroll
        for (int t = 0; t < 2; ++t) {
          const int mt = j * 2 + t;
#pragma unroll
          for (int r = 0; r < 4; ++r) {
            const float e = __builtin_amdgcn_exp2f(
                __builtin_fmaf(acc[mt][r], L2E2, kb1[mt][r]));
            P = __builtin_fmaf(w2m[mt][r], __builtin_amdgcn_rcpf(e + 1.0f), P);
          }
        }
        P += __shfl_xor(P, 16);
        P += __shfl_xor(P, 32);
        const float arg = __builtin_fmaf(P, L2E2, KSb[j]);
        const float o = 1.0f - __builtin_amdgcn_rcpf(
            __builtin_amdgcn_exp2f(arg) + 1.0f);
        if (j == 0) o0 = o; else o1 = o;
      }

      if (q == 0) {  // 16 lanes store float2 {k=2w,2w+1} for rows tt*16+m16
        float2 st; st.x = o0; st.y = o1;
        *(float2*)(out + (base + tt * 16 + m16) * 8 + wave * 2) = st;
      }
    }
  }
}

extern "C" void kernel_launch(void* const* d_in, const int* in_sizes, int n_in,
                              void* d_out, int out_size, void* d_ws, size_t ws_size,
                              hipStream_t stream) {
  const float* x  = (const float*)d_in[0];
  const float* W1 = (const float*)d_in[1];
  const float* b1 = (const float*)d_in[2];
  const float* W2 = (const float*)d_in[3];
  const float* b2 = (const float*)d_in[4];
  float* out = (float*)d_out;
  fused_mlp8<<<GRID, 256, 0, stream>>>(x, W1, b1, W2, b2, out);
}

// Round 4
// 208.926 us; speedup vs baseline: 1.1267x; 1.1267x over previous
//
#include <hip/hip_runtime.h>

typedef __attribute__((ext_vector_type(8))) short short8;   // 8 bf16 (4 VGPRs) MFMA A/B frag
typedef __attribute__((ext_vector_type(4))) float f32x4;    // MFMA C/D frag

constexpr int B_ROWS   = 524288;
constexpr int ROWTILES = B_ROWS / 64;   // 8192 tiles of 64 rows
constexpr int GRID     = 2048;          // 4 grid-stride iters per block
constexpr float L2E2   = 2.8853900817779268f;  // 2*log2(e)

union V16 { uint4 u; short8 s; };

// round-half-up bf16 pair pack: (bits+0x8000)>>16, two elems -> one u32 via v_perm.
// max rel err 2^-9 (same magnitude as RNE); 2 VALU ops per pair vs 6 for manual RNE.
__device__ __forceinline__ unsigned pk(float lo, float hi) {
  const unsigned a = __float_as_uint(lo) + 0x8000u;
  const unsigned b = __float_as_uint(hi) + 0x8000u;
  return __builtin_amdgcn_perm(b, a, 0x07060302u);  // dst = [a.hi16, b.hi16]
}

__device__ __forceinline__ V16 pk8(f32x4 a, f32x4 b) {
  V16 v;
  v.u.x = pk(a[0], a[1]); v.u.y = pk(a[2], a[3]);
  v.u.z = pk(b[0], b[1]); v.u.w = pk(b[2], b[3]);
  return v;
}

// C[n,b] = sum_i (L*W1[n,i])*x[b,i]  (L=2log2e folded into packed W1)
// out[b,k] = 1 - 1/(exp2(L*S)+1), S = b2 + sum_h w2 - sum_h 2*w2/(exp2(acc+L*b1)+1)
// Wave w owns n in [64w,64w+64) -> classifiers {2w,2w+1}; weights in registers.
// x staged once/tile into LDS bf16 (pack once per element), XOR-swizzled so all
// ds accesses are conflict-free; outputs staged in LDS -> full-line float2 stores.
__global__ __launch_bounds__(256, 4) void fused_mlp8(
    const float* __restrict__ x, const float* __restrict__ W1,
    const float* __restrict__ b1, const float* __restrict__ W2,
    const float* __restrict__ b2, float* __restrict__ out) {

  // 64 rows x 8 chunks(16B); chunk c of row r stored at r*8 + (c ^ (r&7))
  __shared__ V16 xbuf[512];
  __shared__ float obuf[64 * 10];   // out staging, rows padded to 10 floats

  const int tid  = threadIdx.x;
  const int wave = tid >> 6;
  const int lane = tid & 63;
  const int m16  = lane & 15;
  const int q    = lane >> 4;

  // ---- W1 A-fragments (scaled by L2E2): lane holds rows n=(4w+mt)*16+m16
  short8 w1f[4][2];
#pragma unroll
  for (int mt = 0; mt < 4; ++mt) {
    const int n = (wave * 4 + mt) * 16 + m16;
#pragma unroll
    for (int ks = 0; ks < 2; ++ks) {
      const float* p = W1 + n * 64 + ks * 32 + q * 8;
      const f32x4 u0 = *(const f32x4*)p, u1 = *(const f32x4*)(p + 4);
      f32x4 s0, s1;
#pragma unroll
      for (int r = 0; r < 4; ++r) { s0[r] = L2E2 * u0[r]; s1[r] = L2E2 * u1[r]; }
      w1f[mt][ks] = pk8(s0, s1).s;
    }
  }

  // ---- folded per-lane constants for C-layout rows n0 = (4w+mt)*16 + 4q
  f32x4 kb1[4], w2m[4];
  float sw2[2] = {0.f, 0.f};
#pragma unroll
  for (int mt = 0; mt < 4; ++mt) {
    const int n0 = (wave * 4 + mt) * 16 + q * 4;
    const f32x4 b1x = *(const f32x4*)(b1 + n0);
    const f32x4 w2x = *(const f32x4*)(W2 + n0);
#pragma unroll
    for (int r = 0; r < 4; ++r) {
      kb1[mt][r] = L2E2 * b1x[r];
      w2m[mt][r] = -2.0f * w2x[r];
      sw2[mt >> 1] += w2x[r];
    }
  }
  float KSb[2];
#pragma unroll
  for (int j = 0; j < 2; ++j) {
    float s = sw2[j];
    s += __shfl_xor(s, 16);
    s += __shfl_xor(s, 32);
    KSb[j] = L2E2 * (s + b2[wave * 2 + j]);
  }

  // ---- staging geometry: thread covers row=tid>>2, cols seg*16..+15 (64B)
  const int srow = tid >> 2;
  const int seg  = tid & 3;
  const int sw   = srow & 7;

  // prefetch first tile
  f32x4 pf[4];
  {
    const float* gp = x + ((long)blockIdx.x * 64 + srow) * 64 + seg * 16;
#pragma unroll
    for (int c = 0; c < 4; ++c) pf[c] = *(const f32x4*)(gp + c * 4);
  }

  for (int it = blockIdx.x; it < ROWTILES; it += GRID) {
    // ---- pack prefetched regs -> swizzled LDS bf16
    xbuf[srow * 8 + ((seg * 2)     ^ sw)] = pk8(pf[0], pf[1]);
    xbuf[srow * 8 + ((seg * 2 + 1) ^ sw)] = pk8(pf[2], pf[3]);
    __syncthreads();

    // ---- issue next tile's loads; they land during compute
    if (it + GRID < ROWTILES) {
      const float* gp = x + ((long)(it + GRID) * 64 + srow) * 64 + seg * 16;
#pragma unroll
      for (int c = 0; c < 4; ++c) pf[c] = *(const f32x4*)(gp + c * 4);
    }

#pragma unroll
    for (int tt = 0; tt < 4; ++tt) {
      const int r   = tt * 16 + m16;
      const int rsw = r & 7;
      const short8 xf0 = xbuf[r * 8 + (q       ^ rsw)].s;
      const short8 xf1 = xbuf[r * 8 + ((q + 4) ^ rsw)].s;

      f32x4 acc[4];
#pragma unroll
      for (int mt = 0; mt < 4; ++mt) {
        f32x4 z = { 0.f, 0.f, 0.f, 0.f };
        z = __builtin_amdgcn_mfma_f32_16x16x32_bf16(w1f[mt][0], xf0, z, 0, 0, 0);
        z = __builtin_amdgcn_mfma_f32_16x16x32_bf16(w1f[mt][1], xf1, z, 0, 0, 0);
        acc[mt] = z;
      }

      float o0 = 0.f, o1 = 0.f;
#pragma unroll
      for (int j = 0; j < 2; ++j) {
        float P = 0.f;
#pragma unroll
        for (int t = 0; t < 2; ++t) {
          const int mt = j * 2 + t;
#pragma unroll
          for (int rr = 0; rr < 4; ++rr) {
            const float e = __builtin_amdgcn_exp2f(acc[mt][rr] + kb1[mt][rr]);
            P = __builtin_fmaf(w2m[mt][rr], __builtin_amdgcn_rcpf(e + 1.0f), P);
          }
        }
        P += __shfl_xor(P, 16);
        P += __shfl_xor(P, 32);
        const float arg = __builtin_fmaf(P, L2E2, KSb[j]);
        const float o = 1.0f - __builtin_amdgcn_rcpf(
            __builtin_amdgcn_exp2f(arg) + 1.0f);
        if (j == 0) o0 = o; else o1 = o;
      }

      if (q == 0) {  // stage to LDS (bank-free: stride 10, 16 distinct banks)
        float2 st; st.x = o0; st.y = o1;
        *(float2*)&obuf[r * 10 + wave * 2] = st;
      }
    }
    __syncthreads();

    // ---- cooperative full-line out store: thread t -> row t>>2, floats (t&3)*2..+1
    {
      const int orow = tid >> 2, oc = (tid & 3) * 2;
      const float2 v = *(const float2*)&obuf[orow * 10 + oc];
      *(float2*)(out + ((long)it * 64 + orow) * 8 + oc) = v;
    }
    // next iteration's xbuf writes are pre-barrier1-safe (different array),
    // obuf rewrites happen only after the next __syncthreads()
  }
}

extern "C" void kernel_launch(void* const* d_in, const int* in_sizes, int n_in,
                              void* d_out, int out_size, void* d_ws, size_t ws_size,
                              hipStream_t stream) {
  const float* x  = (const float*)d_in[0];
  const float* W1 = (const float*)d_in[1];
  const float* b1 = (const float*)d_in[2];
  const float* W2 = (const float*)d_in[3];
  const float* b2 = (const float*)d_in[4];
  float* out = (float*)d_out;
  fused_mlp8<<<GRID, 256, 0, stream>>>(x, W1, b1, W2, b2, out);
}

// Round 5
// 207.279 us; speedup vs baseline: 1.1357x; 1.0079x over previous
//
#include <hip/hip_runtime.h>

typedef __attribute__((ext_vector_type(8))) short short8;   // 8 bf16 (4 VGPRs) MFMA A/B frag
typedef __attribute__((ext_vector_type(4))) float f32x4;    // MFMA C/D frag

constexpr int B_ROWS   = 524288;
constexpr int ROWTILES = B_ROWS / 64;   // 8192 tiles of 64 rows
constexpr int GRID     = 2048;
constexpr int ITERS    = ROWTILES / GRID;   // 4 tiles per block
constexpr float L2E2   = 2.8853900817779268f;  // 2*log2(e)

union V16 { uint4 u; short8 s; };

// round-half-up bf16 pair pack: (bits+0x8000)>>16, two elems -> one u32 via v_perm.
__device__ __forceinline__ unsigned pk(float lo, float hi) {
  const unsigned a = __float_as_uint(lo) + 0x8000u;
  const unsigned b = __float_as_uint(hi) + 0x8000u;
  return __builtin_amdgcn_perm(b, a, 0x07060302u);  // dst = [a.hi16, b.hi16]
}

__device__ __forceinline__ V16 pk8(f32x4 a, f32x4 b) {
  V16 v;
  v.u.x = pk(a[0], a[1]); v.u.y = pk(a[2], a[3]);
  v.u.z = pk(b[0], b[1]); v.u.w = pk(b[2], b[3]);
  return v;
}

// Single-barrier software pipeline:
//   iter i: compute tile i from xb[p] -> obuf[p]; pack regs(tile i+1) -> xb[p^1];
//           __syncthreads(); coalesced store obuf[p]; global-load tile i+2 -> regs.
// C[n,b] = sum_i (L*W1[n,i])*x[b,i]; out[b,k] = 1 - 1/(exp2(L*S)+1),
// S = b2 + sum_h w2 - sum_h 2*w2/(exp2(acc + L*b1)+1)   [folded tanh algebra]
__global__ __launch_bounds__(256, 4) void fused_mlp8(
    const float* __restrict__ x, const float* __restrict__ W1,
    const float* __restrict__ b1, const float* __restrict__ W2,
    const float* __restrict__ b2, float* __restrict__ out) {

  // x: 2 buffers x 64 rows x 8 chunks(16B); chunk c of row r at r*8 + (c ^ (r&7))
  __shared__ V16  xb[2][512];
  __shared__ float ob[2][64 * 10];   // out staging, rows padded to 10 floats

  const int tid  = threadIdx.x;
  const int wave = tid >> 6;
  const int lane = tid & 63;
  const int m16  = lane & 15;
  const int q    = lane >> 4;

  // ---- W1 A-fragments (scaled by L2E2): lane holds rows n=(4w+mt)*16+m16
  short8 w1f[4][2];
#pragma unroll
  for (int mt = 0; mt < 4; ++mt) {
    const int n = (wave * 4 + mt) * 16 + m16;
#pragma unroll
    for (int ks = 0; ks < 2; ++ks) {
      const float* p = W1 + n * 64 + ks * 32 + q * 8;
      const f32x4 u0 = *(const f32x4*)p, u1 = *(const f32x4*)(p + 4);
      f32x4 s0, s1;
#pragma unroll
      for (int r = 0; r < 4; ++r) { s0[r] = L2E2 * u0[r]; s1[r] = L2E2 * u1[r]; }
      w1f[mt][ks] = pk8(s0, s1).s;
    }
  }

  // ---- folded per-lane constants for C-layout rows n0 = (4w+mt)*16 + 4q
  f32x4 kb1[4], w2m[4];
  float sw2[2] = {0.f, 0.f};
#pragma unroll
  for (int mt = 0; mt < 4; ++mt) {
    const int n0 = (wave * 4 + mt) * 16 + q * 4;
    const f32x4 b1x = *(const f32x4*)(b1 + n0);
    const f32x4 w2x = *(const f32x4*)(W2 + n0);
#pragma unroll
    for (int r = 0; r < 4; ++r) {
      kb1[mt][r] = L2E2 * b1x[r];
      w2m[mt][r] = -2.0f * w2x[r];
      sw2[mt >> 1] += w2x[r];
    }
  }
  float KSb[2];
#pragma unroll
  for (int j = 0; j < 2; ++j) {
    float s = sw2[j];
    s += __shfl_xor(s, 16);
    s += __shfl_xor(s, 32);
    KSb[j] = L2E2 * (s + b2[wave * 2 + j]);
  }

  // ---- staging geometry: thread covers row=tid>>2, cols seg*16..+15 (64B)
  const int srow = tid >> 2;
  const int seg  = tid & 3;
  const int sw   = srow & 7;
  const float* gbase = x + (long)srow * 64 + seg * 16;

  // ---- prologue: tile0 -> xb[0]; tile1 -> regs
  f32x4 pf[4];
#pragma unroll
  for (int c = 0; c < 4; ++c)
    pf[c] = *(const f32x4*)(gbase + (long)blockIdx.x * 4096 + c * 4);
  xb[0][srow * 8 + ((seg * 2)     ^ sw)] = pk8(pf[0], pf[1]);
  xb[0][srow * 8 + ((seg * 2 + 1) ^ sw)] = pk8(pf[2], pf[3]);
#pragma unroll
  for (int c = 0; c < 4; ++c)
    pf[c] = *(const f32x4*)(gbase + ((long)blockIdx.x + GRID) * 4096 + c * 4);
  __syncthreads();

#pragma unroll
  for (int i = 0; i < ITERS; ++i) {
    const int p = i & 1;
    const long tile = (long)blockIdx.x + (long)i * GRID;

    // ---- compute tile i from xb[p] -> ob[p]
#pragma unroll
    for (int tt = 0; tt < 4; ++tt) {
      const int r   = tt * 16 + m16;
      const int rsw = r & 7;
      const short8 xf0 = xb[p][r * 8 + (q       ^ rsw)].s;
      const short8 xf1 = xb[p][r * 8 + ((q + 4) ^ rsw)].s;

      f32x4 acc[4];
#pragma unroll
      for (int mt = 0; mt < 4; ++mt) {
        f32x4 z = { 0.f, 0.f, 0.f, 0.f };
        z = __builtin_amdgcn_mfma_f32_16x16x32_bf16(w1f[mt][0], xf0, z, 0, 0, 0);
        z = __builtin_amdgcn_mfma_f32_16x16x32_bf16(w1f[mt][1], xf1, z, 0, 0, 0);
        acc[mt] = z;
      }

      float o0 = 0.f, o1 = 0.f;
#pragma unroll
      for (int j = 0; j < 2; ++j) {
        float P = 0.f;
#pragma unroll
        for (int t = 0; t < 2; ++t) {
          const int mt = j * 2 + t;
#pragma unroll
          for (int rr = 0; rr < 4; ++rr) {
            const float e = __builtin_amdgcn_exp2f(acc[mt][rr] + kb1[mt][rr]);
            P = __builtin_fmaf(w2m[mt][rr], __builtin_amdgcn_rcpf(e + 1.0f), P);
          }
        }
        P += __shfl_xor(P, 16);
        P += __shfl_xor(P, 32);
        const float arg = __builtin_fmaf(P, L2E2, KSb[j]);
        const float o = 1.0f - __builtin_amdgcn_rcpf(
            __builtin_amdgcn_exp2f(arg) + 1.0f);
        if (j == 0) o0 = o; else o1 = o;
      }

      if (q == 0) {  // stage to LDS (stride-10 rows: conflict-free)
        float2 st; st.x = o0; st.y = o1;
        *(float2*)&ob[p][r * 10 + wave * 2] = st;
      }
    }

    // ---- pack tile i+1 regs -> xb[p^1] (overlaps compute; pre-barrier)
    if (i + 1 < ITERS) {
      xb[p ^ 1][srow * 8 + ((seg * 2)     ^ sw)] = pk8(pf[0], pf[1]);
      xb[p ^ 1][srow * 8 + ((seg * 2 + 1) ^ sw)] = pk8(pf[2], pf[3]);
    }

    __syncthreads();   // the ONLY barrier per iteration

    // ---- coalesced store of tile i (thread t -> row t>>2, floats (t&3)*2..+1)
    {
      const int orow = tid >> 2, oc = (tid & 3) * 2;
      const float2 v = *(const float2*)&ob[p][orow * 10 + oc];
      *(float2*)(out + (tile * 64 + orow) * 8 + oc) = v;
    }

    // ---- issue tile i+2 loads; consumed at iteration i+1's pack
    if (i + 2 < ITERS) {
      const float* gp = gbase + (tile + 2 * GRID) * 4096;
#pragma unroll
      for (int c = 0; c < 4; ++c) pf[c] = *(const f32x4*)(gp + c * 4);
    }
  }
}

extern "C" void kernel_launch(void* const* d_in, const int* in_sizes, int n_in,
                              void* d_out, int out_size, void* d_ws, size_t ws_size,
                              hipStream_t stream) {
  const float* x  = (const float*)d_in[0];
  const float* W1 = (const float*)d_in[1];
  const float* b1 = (const float*)d_in[2];
  const float* W2 = (const float*)d_in[3];
  const float* b2 = (const float*)d_in[4];
  float* out = (float*)d_out;
  fused_mlp8<<<GRID, 256, 0, stream>>>(x, W1, b1, W2, b2, out);
}